// Round 1
// baseline (53.827 us; speedup 1.0000x reference)
//
#include <hip/hip_runtime.h>
#include <math.h>

#define DIM 9
#define SINE_AMP 0.1f
#define NOISE_STD 0.003f

// ---------------------------------------------------------------------------
// Kernel 1: one wave per (b, d) chain.
// Computes rad[b,l,d] with exact f32 reference semantics, and
// base[b,l,d] = frac( upp * sum_{l' < l} rad[b,l',d] )  (double-precision scan).
// ---------------------------------------------------------------------------
__global__ void __launch_bounds__(64)
phase_scan_kernel(const float* __restrict__ f0,
                  const float* __restrict__ rand_ini,
                  float* __restrict__ rad_out,
                  float* __restrict__ base_out,
                  int B, int L, int upp)
{
    const int bd   = blockIdx.x;        // b*DIM + d
    const int b    = bd / DIM;
    const int d    = bd - b * DIM;
    const int lane = threadIdx.x;       // 0..63
    const float hf = (float)(d + 1);
    const float ri = (d == 0) ? 0.0f : rand_ini[b * DIM + d];

    double carry = 0.0;
    for (int c0 = 0; c0 < L; c0 += 64) {
        const int l = c0 + lane;
        float r = 0.0f;
        if (l < L) {
            // reference: f0_buf = f0 * h (f32);  rad = (f0_buf / SR) % 1.0 (f32)
            float fb = f0[b * L + l] * hf;
            r = fmodf(fb / 48000.0f, 1.0f);
            if (l == 0) r += ri;        // rand_ini added at frame 0 (f32 add)
        }
        const double rd = (double)r;
        double inc = rd;
        // wave-64 inclusive scan in double
        #pragma unroll
        for (int off = 1; off < 64; off <<= 1) {
            double t = __shfl_up(inc, off, 64);
            if (lane >= off) inc += t;
        }
        if (l < L) {
            const double excl = carry + (inc - rd);   // exclusive prefix
            double bf = excl * (double)upp;
            bf -= floor(bf);                          // frac in double, exact enough
            const int idx = (b * L + l) * DIM + d;
            rad_out[idx]  = r;
            base_out[idx] = (float)bf;
        }
        carry += __shfl(inc, 63, 64);
    }
}

// ---------------------------------------------------------------------------
// Kernel 2: fully parallel sample generation.
// flat element idx within batch b: rem = o*DIM + d ; o = l*upp + j
// sine = 0.1*sin(2*pi*frac(base[l] + (j+1)*rad[l])) * uv + noise
// ---------------------------------------------------------------------------
template <int UPP>
__global__ void __launch_bounds__(256)
sine_gen_kernel(const float* __restrict__ f0,
                const float* __restrict__ noise_randn,
                const float* __restrict__ rad_arr,
                const float* __restrict__ base_arr,
                float* __restrict__ out_sine,
                float* __restrict__ out_uv,
                float* __restrict__ out_noise,
                int L, int Lo, int upp)
{
    const int b   = blockIdx.y;
    const int LoD = Lo * DIM;
    const int n4  = LoD >> 2;
    const long long boff = (long long)b * LoD;

    const float* __restrict__ nz_b    = noise_randn + boff;
    float* __restrict__       sine_b  = out_sine + boff;
    float* __restrict__       noise_b = out_noise + boff;
    const float* __restrict__ f0_b    = f0 + b * L;
    float* __restrict__       uv_b    = out_uv + (long long)b * Lo;
    const int fbase = b * L * DIM;

    for (int i4 = blockIdx.x * blockDim.x + threadIdx.x; i4 < n4;
         i4 += gridDim.x * blockDim.x) {
        const int i0 = i4 << 2;
        const float4 nr = *(const float4*)(nz_b + i0);
        const float nrk[4] = {nr.x, nr.y, nr.z, nr.w};
        float sv[4], nv[4];
        #pragma unroll
        for (int k = 0; k < 4; ++k) {
            const int rem = i0 + k;
            const int o = rem / DIM;           // DIM compile-time -> magic mul
            const int d = rem - o * DIM;
            int l, j;
            if (UPP > 0) { l = o / UPP; j = o - l * UPP; }   // shift when pow2
            else         { l = o / upp; j = o - l * upp; }
            const int fidx = fbase + l * DIM + d;
            const float rad  = rad_arr[fidx];
            const float base = base_arr[fidx];
            float ph = base + (float)(j + 1) * rad;
            ph -= floorf(ph);                  // ph in [0,1) revolutions
            float s;
            // v_sin_f32 takes revolutions: D = sin(S0 * 2*pi)
            asm("v_sin_f32 %0, %1" : "=v"(s) : "v"(ph));
            const float f0v  = f0_b[l];
            const float uvf  = (f0v > 0.0f) ? 1.0f : 0.0f;
            const float namp = uvf * NOISE_STD + (1.0f - uvf) * (SINE_AMP / 3.0f);
            const float nzv  = namp * nrk[k];
            nv[k] = nzv;
            sv[k] = s * SINE_AMP * uvf + nzv;
            if (d == 0) uv_b[o] = uvf;
        }
        *(float4*)(sine_b + i0)  = make_float4(sv[0], sv[1], sv[2], sv[3]);
        *(float4*)(noise_b + i0) = make_float4(nv[0], nv[1], nv[2], nv[3]);
    }

    // tail (LoD not divisible by 4 — not hit for upp=512, cheap insurance)
    if (blockIdx.x == 0 && threadIdx.x < (LoD & 3)) {
        const int rem = (n4 << 2) + threadIdx.x;
        const int o = rem / DIM;
        const int d = rem - o * DIM;
        int l, j;
        if (UPP > 0) { l = o / UPP; j = o - l * UPP; }
        else         { l = o / upp; j = o - l * upp; }
        const int fidx = fbase + l * DIM + d;
        float ph = base_arr[fidx] + (float)(j + 1) * rad_arr[fidx];
        ph -= floorf(ph);
        float s;
        asm("v_sin_f32 %0, %1" : "=v"(s) : "v"(ph));
        const float f0v  = f0_b[l];
        const float uvf  = (f0v > 0.0f) ? 1.0f : 0.0f;
        const float namp = uvf * NOISE_STD + (1.0f - uvf) * (SINE_AMP / 3.0f);
        const float nzv  = namp * nz_b[rem];
        noise_b[rem] = nzv;
        sine_b[rem]  = s * SINE_AMP * uvf + nzv;
        if (d == 0) uv_b[o] = uvf;
    }
}

extern "C" void kernel_launch(void* const* d_in, const int* in_sizes, int n_in,
                              void* d_out, int out_size, void* d_ws, size_t ws_size,
                              hipStream_t stream)
{
    const float* f0       = (const float*)d_in[0];
    const float* rand_ini = (const float*)d_in[1];
    const float* noise    = (const float*)d_in[2];
    // d_in[3] is upp on device; derive all dims from in_sizes instead.
    const int B  = in_sizes[1] / DIM;        // rand_ini is (B, DIM)
    const int L  = in_sizes[0] / B;          // f0 is (B, L)
    const int Lo = in_sizes[2] / (B * DIM);  // noise_randn is (B, Lo, DIM)
    const int upp = Lo / L;

    float* out       = (float*)d_out;
    float* out_sine  = out;
    float* out_uv    = out_sine + (long long)B * Lo * DIM;
    float* out_noise = out_uv + (long long)B * Lo;

    float* rad_ws  = (float*)d_ws;
    float* base_ws = rad_ws + (size_t)B * L * DIM;

    phase_scan_kernel<<<dim3(B * DIM), dim3(64), 0, stream>>>(
        f0, rand_ini, rad_ws, base_ws, B, L, upp);

    const int n4 = (Lo * DIM) >> 2;
    int bx = (n4 + 255) / 256;
    if (bx > 1024) bx = 1024;
    dim3 grid(bx, B);
    if (upp == 512) {
        sine_gen_kernel<512><<<grid, dim3(256), 0, stream>>>(
            f0, noise, rad_ws, base_ws, out_sine, out_uv, out_noise, L, Lo, upp);
    } else {
        sine_gen_kernel<0><<<grid, dim3(256), 0, stream>>>(
            f0, noise, rad_ws, base_ws, out_sine, out_uv, out_noise, L, Lo, upp);
    }
}